// Round 4
// baseline (178.677 us; speedup 1.0000x reference)
//
#include <hip/hip_runtime.h>
#include <math.h>

#define NN 2048          // N_NODES
#define NE 65536         // N_EDGES
#define DM 256           // D_MODEL
#define NH 8             // NHEAD
#define DKH 32           // DK
#define CAP 128          // per-row edge-list capacity
#define TM2 128          // attention m-tile
#define SPLIT 4          // attention m-split (partial-sum buffers)

typedef __attribute__((ext_vector_type(8))) short bf16x8;   // 8 bf16 in 4 VGPRs
typedef __attribute__((ext_vector_type(4))) float f32x4;

#define WAVE_LDS_SYNC() __asm__ volatile("s_waitcnt lgkmcnt(0)" ::: "memory")

__device__ __forceinline__ unsigned short f2b(float f) {
    unsigned u = __float_as_uint(f);
    unsigned r = (u + 0x7FFFu + ((u >> 16) & 1u)) >> 16;    // RNE
    return (unsigned short)r;
}
__device__ __forceinline__ float b2f(unsigned short s) {
    return __uint_as_float(((unsigned)s) << 16);
}
// pack two f32 -> two bf16 (round-half-up; cheap: 5 VALU per 2 values)
__device__ __forceinline__ unsigned pk2(float a, float b) {
    unsigned ua = __float_as_uint(a) + 0x8000u;
    unsigned ub = __float_as_uint(b) + 0x8000u;
    return (ua >> 16) | (ub & 0xFFFF0000u);
}

// 64x64 coalesced transpose tile: dst[(n0d+nn)*dstK + k0s+tx] = f2b(src[(k0s+tx)*srcStride + nc0+nn])
__device__ __forceinline__ void transpose_tile(
    const float* __restrict__ src, int srcStride, int nc0, int k0s,
    unsigned short* __restrict__ dst, int dstK, int n0d, int tid)
{
    __shared__ unsigned short T[64][66];   // stride 132B -> bank tx%32 on write, 2-way on read
    int tx = tid & 63, ty = tid >> 6;      // 4 rows per iteration
#pragma unroll
    for (int r = 0; r < 16; ++r) {
        int kk = ty + r * 4;
        T[tx][kk] = f2b(src[(size_t)(k0s + kk) * srcStride + nc0 + tx]);
    }
    __syncthreads();
#pragma unroll
    for (int r = 0; r < 16; ++r) {
        int nn = ty + r * 4;
        dst[(size_t)(n0d + nn) * dstK + k0s + tx] = T[nn][tx];
    }
}

// ------------------------------------------------ fused prep:
// blocks [0,128): LDS-tiled coalesced weight transposes
// blocks [128,384): h -> bf16 (coalesced, 8 elems/thread)
// blocks [384,640): edge bias + per-row edge lists
__global__ __launch_bounds__(256) void prep_all_kernel(
    const float* __restrict__ Wq, const float* __restrict__ Wk,
    const float* __restrict__ Wv, const float* __restrict__ Wo,
    const float* __restrict__ W1, const float* __restrict__ W2,
    const float* __restrict__ h, const float* __restrict__ ea,
    const float* __restrict__ We, const float* __restrict__ be,
    const int* __restrict__ ei,
    unsigned short* __restrict__ Wqkvt, unsigned short* __restrict__ Wot,
    unsigned short* __restrict__ W1t, unsigned short* __restrict__ W2t,
    unsigned short* __restrict__ hb,
    float* __restrict__ eb, int* __restrict__ cnt, int* __restrict__ lst)
{
    int b = blockIdx.x;
    if (b < 128) {
        const float* src; int srcStride, nc0, k0s, dstK, n0d;
        unsigned short* dst;
        if (b < 48) {                      // Wqkv: out 768x256
            int tn = b >> 2, tk = b & 3, n0 = tn * 64;
            src = (n0 < 256) ? Wq : (n0 < 512) ? Wk : Wv;
            srcStride = 256; nc0 = n0 & 255; k0s = tk * 64;
            dst = Wqkvt; dstK = 256; n0d = n0;
        } else if (b < 64) {               // Wo: out 256x256
            int t = b - 48, tn = t >> 2, tk = t & 3;
            src = Wo; srcStride = 256; nc0 = tn * 64; k0s = tk * 64;
            dst = Wot; dstK = 256; n0d = tn * 64;
        } else if (b < 96) {               // W1: out 512x256 (src 256x512)
            int t = b - 64, tn = t >> 2, tk = t & 3;
            src = W1; srcStride = 512; nc0 = tn * 64; k0s = tk * 64;
            dst = W1t; dstK = 256; n0d = tn * 64;
        } else {                           // W2: out 256x512 (src 512x256)
            int t = b - 96, tn = t >> 3, tk = t & 7;
            src = W2; srcStride = 256; nc0 = tn * 64; k0s = tk * 64;
            dst = W2t; dstK = 512; n0d = tn * 64;
        }
        transpose_tile(src, srcStride, nc0, k0s, dst, dstK, n0d, threadIdx.x);
    } else if (b < 384) {
        int j = ((b - 128) * 256 + threadIdx.x) * 8;     // 256 blocks cover 2048*256
        const float* hp = h + j;
        float4 f0 = *(const float4*)hp, f1 = *(const float4*)(hp + 4);
        uint4 pk = { pk2(f0.x, f0.y), pk2(f0.z, f0.w),
                     pk2(f1.x, f1.y), pk2(f1.z, f1.w) };
        *(uint4*)(hb + j) = pk;
    } else {
        int e = (b - 384) * 256 + threadIdx.x;
        float acc[NH];
#pragma unroll
        for (int hh = 0; hh < NH; ++hh) acc[hh] = be[hh];
#pragma unroll
        for (int f = 0; f < 7; ++f) {
            float x = ea[e * 7 + f];
#pragma unroll
            for (int hh = 0; hh < NH; ++hh) acc[hh] = fmaf(x, We[f * NH + hh], acc[hh]);
        }
#pragma unroll
        for (int hh = 0; hh < NH; ++hh)
            eb[e * NH + hh] = acc[hh] * 1.44269504088896f;   // pre-scale by log2(e)
        int s = ei[e];
        int p = atomicAdd(&cnt[s], 1);
        if (p < CAP) lst[s * CAP + p] = e;
    }
}

// per-row: dedup (winner = max edge id per dest) + bucket by m-tile (dest>>7)
__global__ __launch_bounds__(128) void rowprep_kernel(
    const int* __restrict__ ei, const int* __restrict__ cnt,
    const int* __restrict__ lst, int* __restrict__ sortedDest,
    int* __restrict__ sortedE, int* __restrict__ rowOff)
{
    __shared__ int ds[CAP], es[CAP];
    __shared__ int bc[16], off[17];
    int n = blockIdx.x, t = threadIdx.x;
    int c = cnt[n]; if (c > CAP) c = CAP;
    if (t < 16) bc[t] = 0;
    int e = -1, d = -1;
    if (t < c) { e = lst[n * CAP + t]; d = ei[NE + e]; }
    ds[t] = d; es[t] = e;
    __syncthreads();
    bool win = (t < c);
    if (win) {
        for (int j = 0; j < c; ++j)
            if (ds[j] == d && es[j] > e) { win = false; break; }
    }
    int bkt = (d >= 0) ? (d >> 7) : 0;
    int pos = -1;
    if (win) pos = atomicAdd(&bc[bkt], 1);
    __syncthreads();
    if (t == 0) {
        int s = 0;
        for (int i = 0; i < 16; ++i) { off[i] = s; s += bc[i]; }
        off[16] = s;
    }
    __syncthreads();
    if (win) {
        int p = off[bkt] + pos;
        sortedDest[n * CAP + p] = d;
        sortedE[n * CAP + p] = e;
    }
    if (t < 17) rowOff[n * 17 + t] = off[t];
}

// ---------------------------------------------------------------- MFMA GEMM
// C[M,N] = A[M,K] @ Bt[N,K]^T + bias. Tile MT(M) x 64(N), BK=128 chunks.
// EPI 2: QKV split epilogue. Q/K written HEAD-BLOCKED [NH][NN][32] (head is
// uniform per 16-col group; 16-lane 32B write segments unchanged). V transposed.
template <int EPI, int MT, int AF32>
__global__ __launch_bounds__(MT * 4) void gemm_bf16(
    const void* __restrict__ Av, const unsigned short* __restrict__ Bt,
    const float* __restrict__ bias0, const float* __restrict__ bias1,
    const float* __restrict__ bias2, const float* __restrict__ resid,
    void* __restrict__ out0, void* __restrict__ out1, void* __restrict__ out2,
    int M, int N, int K)
{
    __shared__ __align__(16) unsigned short As[MT][136];
    __shared__ __align__(16) unsigned short Bs[64][136];
    int tid = threadIdx.x;
    int wv = tid >> 6, l = tid & 63, l15 = l & 15, quad = l >> 4;
    int m0 = blockIdx.y * MT, n0 = blockIdx.x * 64;

    f32x4 acc[4];
#pragma unroll
    for (int i = 0; i < 4; ++i) acc[i] = (f32x4){0.f, 0.f, 0.f, 0.f};

    for (int k0 = 0; k0 < K; k0 += 128) {
        if (MT == 64) {
            int row = tid >> 2, cb = (tid & 3) * 32;
            if (AF32) {
                const float* ap = (const float*)Av + (size_t)(m0 + row) * K + k0 + cb;
#pragma unroll
                for (int i = 0; i < 4; ++i) {
                    float4 f0 = *(const float4*)(ap + i * 8);
                    float4 f1 = *(const float4*)(ap + i * 8 + 4);
                    uint4 pk = { pk2(f0.x, f0.y), pk2(f0.z, f0.w),
                                 pk2(f1.x, f1.y), pk2(f1.z, f1.w) };
                    *(uint4*)&As[row][cb + i * 8] = pk;
                }
            } else {
                const unsigned short* ap =
                    (const unsigned short*)Av + (size_t)(m0 + row) * K + k0 + cb;
#pragma unroll
                for (int i = 0; i < 4; ++i)
                    *(uint4*)&As[row][cb + i * 8] = *(const uint4*)(ap + i * 8);
            }
            const unsigned short* bp = Bt + (size_t)(n0 + row) * K + k0 + cb;
#pragma unroll
            for (int i = 0; i < 4; ++i)
                *(uint4*)&Bs[row][cb + i * 8] = *(const uint4*)(bp + i * 8);
        } else {
            int rowa = tid >> 2, cba = (tid & 3) * 32;       // 32 A rows
            const unsigned short* ap =
                (const unsigned short*)Av + (size_t)(m0 + rowa) * K + k0 + cba;
#pragma unroll
            for (int i = 0; i < 4; ++i)
                *(uint4*)&As[rowa][cba + i * 8] = *(const uint4*)(ap + i * 8);
            int rowb = tid >> 1, cbb = (tid & 1) * 64;       // 64 B rows
            const unsigned short* bp = Bt + (size_t)(n0 + rowb) * K + k0 + cbb;
#pragma unroll
            for (int i = 0; i < 8; ++i)
                *(uint4*)&Bs[rowb][cbb + i * 8] = *(const uint4*)(bp + i * 8);
        }
        __syncthreads();
#pragma unroll
        for (int ks = 0; ks < 4; ++ks) {
            bf16x8 a = *(const bf16x8*)&As[wv * 16 + l15][ks * 32 + quad * 8];
#pragma unroll
            for (int nt = 0; nt < 4; ++nt) {
                bf16x8 b = *(const bf16x8*)&Bs[nt * 16 + l15][ks * 32 + quad * 8];
                acc[nt] = __builtin_amdgcn_mfma_f32_16x16x32_bf16(a, b, acc[nt], 0, 0, 0);
            }
        }
        __syncthreads();
    }

#pragma unroll
    for (int nt = 0; nt < 4; ++nt) {
        int colb = n0 + nt * 16;                     // uniform per nt
        if (EPI == 2 && colb >= 512) {
            // V: write transposed into Vt[n][NN], rows quad*4..+3 packed
            int n = colb + l15 - 512;
            float bv = bias2[n];
            uint2 pk = { pk2(acc[nt][0] + bv, acc[nt][1] + bv),
                         pk2(acc[nt][2] + bv, acc[nt][3] + bv) };
            *(uint2*)((unsigned short*)out2 + (size_t)n * NN + m0 + wv * 16 + quad * 4) = pk;
            continue;
        }
#pragma unroll
        for (int r = 0; r < 4; ++r) {
            int row = m0 + wv * 16 + quad * 4 + r;
            int col = colb + l15;
            float v = acc[nt][r];
            if (EPI == 0) {
                v += bias0[col];
                if (resid) v += resid[(size_t)row * N + col];
                ((float*)out0)[(size_t)row * N + col] = v;
            } else if (EPI == 1) {
                v += bias0[col];
                v = 0.5f * v * (1.0f + erff(v * 0.70710678118654752f));
                ((unsigned short*)out0)[(size_t)row * N + col] = f2b(v);
            } else {
                if (col < 256) {
                    // fold 1/sqrt(32) * log2(e) into Q; head-blocked layout
                    v = (v + bias0[col]) * 0.2550348592f;
                    ((unsigned short*)out0)[(size_t)(col >> 5) * (NN * 32)
                        + (size_t)row * 32 + (col & 31)] = f2b(v);
                } else {
                    int kc = col - 256;
                    v += bias1[kc];
                    ((unsigned short*)out1)[(size_t)(kc >> 5) * (NN * 32)
                        + (size_t)row * 32 + (kc & 31)] = f2b(v);
                }
            }
        }
    }
}

// ---------------------------------------------------------------- attention
// Barrier-free: K and V^T are L2-resident (128 KB/head) -> MFMA operands are
// loaded DIRECTLY from global (head-blocked K: each 16-lane group reads one
// contiguous 1KB block). Only Pn (wave-private P tile) lives in LDS, synced
// with wave-level lgkmcnt only. No __syncthreads anywhere in the loop; waves
// are fully independent and the compiler pipelines tile t+1 loads under t.
// Values bit-identical to the staged version (same bf16 inputs, same MFMAs).
// grid (NN/64, NH, SPLIT), block 256 = 4 waves x 16 q-rows.
__global__ __launch_bounds__(256) void attn_mfma(
    const unsigned short* __restrict__ Qb, const unsigned short* __restrict__ Kb,
    const unsigned short* __restrict__ Vt, const float* __restrict__ eb,
    const int* __restrict__ sortedDest, const int* __restrict__ sortedE,
    const int* __restrict__ rowOff,
    float* __restrict__ accD, float* __restrict__ lD)
{
    __shared__ __align__(16) unsigned short Pn[4][16][TM2 + 16];  // per-wave P, [qrow][m]
    int h = blockIdx.y, tid = threadIdx.x;
    int wv = tid >> 6, l = tid & 63, l15 = l & 15, quad = l >> 4;
    int n0 = blockIdx.x * 64 + wv * 16;
    int mz = blockIdx.z;

    const unsigned short* Qh = Qb + (size_t)h * NN * 32;
    const unsigned short* Kh = Kb + (size_t)h * NN * 32;
    bf16x8 aq = *(const bf16x8*)(Qh + (size_t)(n0 + l15) * 32 + quad * 8);

    f32x4 oacc[2];
    oacc[0] = (f32x4){0.f, 0.f, 0.f, 0.f};
    oacc[1] = (f32x4){0.f, 0.f, 0.f, 0.f};
    float lacc = 0.f;                               // partial for q-row l15
    float dreg = 0.f;                               // fixup delta, row r16
    const unsigned short* Vth = Vt + (size_t)h * 32 * NN;

    int r16 = l >> 2, sub = l & 3;                  // fixup: 4 lanes per q-row
    int frow = n0 + r16;

    for (int t = 0; t < NN / (TM2 * SPLIT); ++t) {
        int m0 = (mz * (NN / SPLIT)) + t * TM2;
        int ti = m0 >> 7;                           // global tile index 0..15
        // S^T = K Q^T, p = 2^s; K-fragments direct from global (L2 hit)
#pragma unroll
        for (int mt = 0; mt < TM2 / 16; ++mt) {
            bf16x8 ak = *(const bf16x8*)(Kh + (size_t)(m0 + mt * 16 + l15) * 32 + quad * 8);
            f32x4 s = __builtin_amdgcn_mfma_f32_16x16x32_bf16(
                ak, aq, (f32x4){0.f, 0.f, 0.f, 0.f}, 0, 0, 0);
            float p0 = __builtin_amdgcn_exp2f(s[0]);
            float p1 = __builtin_amdgcn_exp2f(s[1]);
            float p2 = __builtin_amdgcn_exp2f(s[2]);
            float p3 = __builtin_amdgcn_exp2f(s[3]);
            lacc += (p0 + p1) + (p2 + p3);
            *(uint2*)&Pn[wv][l15][mt * 16 + quad * 4] =
                (uint2){pk2(p0, p1), pk2(p2, p3)};
        }
        WAVE_LDS_SYNC();   // Pn is wave-private: wave-local visibility suffices
        // sparse bias fixup: P[row][d] *= 2^b; dreg += p_old*(2^b - 1)
        {
            int o0 = rowOff[frow * 17 + ti];
            int o1 = rowOff[frow * 17 + ti + 1];
            for (int idx = o0 + sub; idx < o1; idx += 4) {
                int d = sortedDest[frow * CAP + idx] - m0;   // 0..127
                int e = sortedE[frow * CAP + idx];
                float expb = __builtin_amdgcn_exp2f(eb[e * NH + h]);
                float pold = b2f(Pn[wv][r16][d]);
                Pn[wv][r16][d] = f2b(pold * expb);
                dreg += pold * (expb - 1.0f);
            }
        }
        WAVE_LDS_SYNC();
        // O += P @ V  (A-frags from Pn, B-frags direct from global V^T, L2 hit)
#pragma unroll
        for (int kc = 0; kc < TM2 / 32; ++kc) {
            bf16x8 ap = *(const bf16x8*)&Pn[wv][l15][kc * 32 + quad * 8];
#pragma unroll
            for (int nt = 0; nt < 2; ++nt) {
                bf16x8 bv = *(const bf16x8*)(Vth
                    + (size_t)(nt * 16 + l15) * NN + m0 + kc * 32 + quad * 8);
                oacc[nt] = __builtin_amdgcn_mfma_f32_16x16x32_bf16(ap, bv, oacc[nt], 0, 0, 0);
            }
        }
        WAVE_LDS_SYNC();   // PV ds_reads drained before next iter's Pn writes
    }

    // reduce: lacc over quads; dreg over the 4 sub-lanes of each row
    lacc += __shfl_xor(lacc, 16);
    lacc += __shfl_xor(lacc, 32);
    dreg += __shfl_xor(dreg, 1);
    dreg += __shfl_xor(dreg, 2);
    float dtot = __shfl(dreg, l15 * 4);             // row l15's total delta
    float* lDp = lD + (size_t)mz * NN * NH;
    if (l < 16)
        lDp[(size_t)(n0 + l) * NH + h] = lacc + dtot;
    float* aDp = accD + (size_t)mz * NN * DM;
#pragma unroll
    for (int nt = 0; nt < 2; ++nt)
#pragma unroll
        for (int r = 0; r < 4; ++r)
            aDp[(size_t)(n0 + quad * 4 + r) * DM + h * 32 + nt * 16 + l15] = oacc[nt][r];
}

// ------------------------------------------- fused tail (barrier-free GEMMs):
// T = h + (sum accD / sum lD) @ Wo + bo ; H1 = LN(T) ; X2 = bf16(LN(H1))
// F1 = gelu(X2 @ W1 + b1) ; out = H1 + F1 @ W2 + b2
// Weights L2-resident: B-fragments loaded directly from global into MFMA
// operands; no barriers inside the K-loops. 512 threads = 8 waves.
__global__ __launch_bounds__(512) void tail_fused_kernel(
    const float* __restrict__ accD, const float* __restrict__ lD,
    const unsigned short* __restrict__ Wot, const float* __restrict__ bo,
    const float* __restrict__ h, const float* __restrict__ ln1g,
    const float* __restrict__ ln1b, const float* __restrict__ flng,
    const float* __restrict__ flnb,
    const unsigned short* __restrict__ W1t, const float* __restrict__ fb1,
    const unsigned short* __restrict__ W2t, const float* __restrict__ fb2,
    float* __restrict__ out)
{
    __shared__ float linv[16][8];
    __shared__ __align__(16) unsigned short As[16][264];    // attn-out bf16
    __shared__ float Tt[16][264];                            // T, then H1 (f32)
    __shared__ __align__(16) unsigned short X2s[16][264];   // LN2 output bf16
    __shared__ __align__(16) unsigned short F1s[16][520];   // gelu output bf16
    int tid = threadIdx.x, m0 = blockIdx.x * 16;
    int wv = tid >> 6, l = tid & 63, l15 = l & 15, quad = l >> 4;

    if (tid < 128) {
        int r = tid >> 3, hh = tid & 7;
        float ls = 0.f;
#pragma unroll
        for (int s = 0; s < SPLIT; ++s)
            ls += lD[(size_t)s * NN * NH + (size_t)(m0 + r) * NH + hh];
        linv[r][hh] = 1.0f / ls;
    }
    __syncthreads();
    {   // As fill: 512 threads cover 2 rows x 256 cols per iteration
        int col = tid & 255, rh = tid >> 8;
#pragma unroll
        for (int ch = 0; ch < 8; ++ch) {
            int row = ch * 2 + rh;
            float o = 0.f;
#pragma unroll
            for (int s = 0; s < SPLIT; ++s)
                o += accD[(size_t)s * NN * DM + (size_t)(m0 + row) * DM + col];
            As[row][col] = f2b(o * linv[row][col >> 5]);
        }
    }
    __syncthreads();

    // ---- GEMM 1: AO @ Wo  (16x256, K=256) — B direct from global, no barriers
    f32x4 acc[2];
    acc[0] = (f32x4){0.f, 0.f, 0.f, 0.f};
    acc[1] = (f32x4){0.f, 0.f, 0.f, 0.f};
#pragma unroll
    for (int k0 = 0; k0 < 256; k0 += 32) {
        bf16x8 a = *(const bf16x8*)&As[l15][k0 + quad * 8];
#pragma unroll
        for (int nt = 0; nt < 2; ++nt) {
            int row = wv * 32 + nt * 16 + l15;
            bf16x8 b = *(const bf16x8*)(Wot + (size_t)row * 256 + k0 + quad * 8);
            acc[nt] = __builtin_amdgcn_mfma_f32_16x16x32_bf16(a, b, acc[nt], 0, 0, 0);
        }
    }
#pragma unroll
    for (int nt = 0; nt < 2; ++nt)
#pragma unroll
        for (int r = 0; r < 4; ++r) {
            int row = quad * 4 + r, col = wv * 32 + nt * 16 + l15;
            Tt[row][col] = acc[nt][r] + bo[col] + h[(size_t)(m0 + row) * DM + col];
        }
    __syncthreads();

    // ---- double LN: 16 lanes per row (waves 0..3, identical to before)
    if (tid < 256) {
        int rr = tid >> 4, l16 = tid & 15;
        float x[16];
#pragma unroll
        for (int j = 0; j < 16; ++j) x[j] = Tt[rr][l16 + 16 * j];
        float mu = 0.f;
#pragma unroll
        for (int j = 0; j < 16; ++j) mu += x[j];
#pragma unroll
        for (int off = 1; off < 16; off <<= 1) mu += __shfl_xor(mu, off);
        mu *= (1.0f / 256.0f);
        float var = 0.f;
#pragma unroll
        for (int j = 0; j < 16; ++j) { float d = x[j] - mu; var += d * d; }
#pragma unroll
        for (int off = 1; off < 16; off <<= 1) var += __shfl_xor(var, off);
        float rs = rsqrtf(var * (1.0f / 256.0f) + 1e-5f);
        float y[16]; float mu2 = 0.f;
#pragma unroll
        for (int j = 0; j < 16; ++j) {
            int c = l16 + 16 * j;
            y[j] = (x[j] - mu) * rs * ln1g[c] + ln1b[c];
            mu2 += y[j];
        }
#pragma unroll
        for (int off = 1; off < 16; off <<= 1) mu2 += __shfl_xor(mu2, off);
        mu2 *= (1.0f / 256.0f);
        float var2 = 0.f;
#pragma unroll
        for (int j = 0; j < 16; ++j) { float d = y[j] - mu2; var2 += d * d; }
#pragma unroll
        for (int off = 1; off < 16; off <<= 1) var2 += __shfl_xor(var2, off);
        float rs2 = rsqrtf(var2 * (1.0f / 256.0f) + 1e-5f);
#pragma unroll
        for (int j = 0; j < 16; ++j) {
            int c = l16 + 16 * j;
            Tt[rr][c] = y[j];                               // H1 (kept for residual)
            X2s[rr][c] = f2b((y[j] - mu2) * rs2 * flng[c] + flnb[c]);
        }
    }
    __syncthreads();

    // ---- GEMM 2: X2 @ W1 -> gelu -> F1s  (16x512, K=256)
    f32x4 acc1[4];
#pragma unroll
    for (int i = 0; i < 4; ++i) acc1[i] = (f32x4){0.f, 0.f, 0.f, 0.f};
#pragma unroll
    for (int k0 = 0; k0 < 256; k0 += 32) {
        bf16x8 a = *(const bf16x8*)&X2s[l15][k0 + quad * 8];
#pragma unroll
        for (int nt = 0; nt < 4; ++nt) {
            int row = wv * 64 + nt * 16 + l15;
            bf16x8 b = *(const bf16x8*)(W1t + (size_t)row * 256 + k0 + quad * 8);
            acc1[nt] = __builtin_amdgcn_mfma_f32_16x16x32_bf16(a, b, acc1[nt], 0, 0, 0);
        }
    }
#pragma unroll
    for (int nt = 0; nt < 4; ++nt)
#pragma unroll
        for (int r = 0; r < 4; ++r) {
            int row = quad * 4 + r, col = wv * 64 + nt * 16 + l15;
            float v = acc1[nt][r] + fb1[col];
            v = 0.5f * v * (1.0f + erff(v * 0.70710678118654752f));
            F1s[row][col] = f2b(v);
        }
    __syncthreads();

    // ---- GEMM 3: F1 @ W2 + b2 + H1 -> out  (16x256, K=512)
    f32x4 acc2[2];
    acc2[0] = (f32x4){0.f, 0.f, 0.f, 0.f};
    acc2[1] = (f32x4){0.f, 0.f, 0.f, 0.f};
#pragma unroll
    for (int k0 = 0; k0 < 512; k0 += 32) {
        bf16x8 a = *(const bf16x8*)&F1s[l15][k0 + quad * 8];
#pragma unroll
        for (int nt = 0; nt < 2; ++nt) {
            int row = wv * 32 + nt * 16 + l15;
            bf16x8 b = *(const bf16x8*)(W2t + (size_t)row * 512 + k0 + quad * 8);
            acc2[nt] = __builtin_amdgcn_mfma_f32_16x16x32_bf16(a, b, acc2[nt], 0, 0, 0);
        }
    }
#pragma unroll
    for (int nt = 0; nt < 2; ++nt)
#pragma unroll
        for (int r = 0; r < 4; ++r) {
            int row = quad * 4 + r, col = wv * 32 + nt * 16 + l15;
            out[(size_t)(m0 + row) * DM + col] = acc2[nt][r] + fb2[col] + Tt[row][col];
        }
}

// ---------------------------------------------------------------- launch
extern "C" void kernel_launch(void* const* d_in, const int* in_sizes, int n_in,
                              void* d_out, int out_size, void* d_ws, size_t ws_size,
                              hipStream_t stream)
{
    const float* h    = (const float*)d_in[0];
    const float* ea   = (const float*)d_in[1];
    const float* Wq   = (const float*)d_in[2];
    const float* bq   = (const float*)d_in[3];
    const float* Wk   = (const float*)d_in[4];
    const float* bk   = (const float*)d_in[5];
    const float* Wv   = (const float*)d_in[6];
    const float* bv   = (const float*)d_in[7];
    const float* Wo   = (const float*)d_in[8];
    const float* bo   = (const float*)d_in[9];
    const float* We   = (const float*)d_in[10];
    const float* be   = (const float*)d_in[11];
    const float* ln1g = (const float*)d_in[12];
    const float* ln1b = (const float*)d_in[13];
    const float* flng = (const float*)d_in[14];
    const float* flnb = (const float*)d_in[15];
    const float* W1   = (const float*)d_in[16];
    const float* b1   = (const float*)d_in[17];
    const float* W2   = (const float*)d_in[18];
    const float* b2   = (const float*)d_in[19];
    const int*   ei   = (const int*)d_in[20];
    float* out = (float*)d_out;

    char* p = (char*)d_ws;
    float* eb   = (float*)p;           p += (size_t)NE * NH * 4;        // 2 MB
    int*   cnt  = (int*)p;             p += (size_t)NN * 4;
    int*   lst  = (int*)p;             p += (size_t)NN * CAP * 4;       // 1 MB
    int*   sD   = (int*)p;             p += (size_t)NN * CAP * 4;       // 1 MB
    int*   sE   = (int*)p;             p += (size_t)NN * CAP * 4;       // 1 MB
    int*   rOff = (int*)p;             p += (size_t)NN * 17 * 4;
    unsigned short* Wqkvt = (unsigned short*)p; p += (size_t)768 * 256 * 2;
    unsigned short* Wot   = (unsigned short*)p; p += (size_t)256 * 256 * 2;
    unsigned short* W1t   = (unsigned short*)p; p += (size_t)512 * 256 * 2;
    unsigned short* W2t   = (unsigned short*)p; p += (size_t)256 * 512 * 2;
    unsigned short* hb    = (unsigned short*)p; p += (size_t)NN * DM * 2;
    unsigned short* Qb    = (unsigned short*)p; p += (size_t)NN * DM * 2;
    unsigned short* Kb    = (unsigned short*)p; p += (size_t)NN * DM * 2;
    unsigned short* Vt    = (unsigned short*)p; p += (size_t)NN * DM * 2;
    float* accD = (float*)p;           p += (size_t)SPLIT * NN * DM * 4; // 8 MB
    float* lD   = (float*)p;           p += (size_t)SPLIT * NN * NH * 4;

    hipMemsetAsync(cnt, 0, (size_t)NN * 4, stream);
    prep_all_kernel<<<384 + NE / 256, 256, 0, stream>>>(
        Wq, Wk, Wv, Wo, W1, W2, h, ea, We, be, ei,
        Wqkvt, Wot, W1t, W2t, hb, eb, cnt, lst);
    rowprep_kernel<<<NN, 128, 0, stream>>>(ei, cnt, lst, sD, sE, rOff);

    // fused QKV: [2048 x 768] = hb(bf16) @ [Wq|Wk|Wv]; Q/K head-blocked out
    gemm_bf16<2, 64, 0><<<dim3(768 / 64, NN / 64), 256, 0, stream>>>(
        hb, Wqkvt, bq, bk, bv, nullptr, Qb, Kb, Vt, NN, 768, 256);

    attn_mfma<<<dim3(NN / 64, NH, SPLIT), 256, 0, stream>>>(
        Qb, Kb, Vt, eb, sD, sE, rOff, accD, lD);

    // fused tail: Wo GEMM + LN1 + LN2 + FFN1 + gelu + FFN2 + residual
    tail_fused_kernel<<<NN / 16, 512, 0, stream>>>(
        accD, lD, Wot, bo, h, ln1g, ln1b, flng, flnb,
        W1t, b1, W2t, b2, out);
}

// Round 6
// 166.134 us; speedup vs baseline: 1.0755x; 1.0755x over previous
//
#include <hip/hip_runtime.h>
#include <math.h>

#define NN 2048          // N_NODES
#define NE 65536         // N_EDGES
#define DM 256           // D_MODEL
#define NH 8             // NHEAD
#define DKH 32           // DK
#define CAP 128          // per-row edge-list capacity
#define TM2 128          // attention m-tile
#define SPLIT 4          // attention m-split (partial-sum buffers)

typedef __attribute__((ext_vector_type(8))) short bf16x8;   // 8 bf16 in 4 VGPRs
typedef __attribute__((ext_vector_type(4))) float f32x4;

#define WAVE_LDS_SYNC() __asm__ volatile("s_waitcnt lgkmcnt(0)" ::: "memory")

__device__ __forceinline__ unsigned short f2b(float f) {
    unsigned u = __float_as_uint(f);
    unsigned r = (u + 0x7FFFu + ((u >> 16) & 1u)) >> 16;    // RNE
    return (unsigned short)r;
}
__device__ __forceinline__ float b2f(unsigned short s) {
    return __uint_as_float(((unsigned)s) << 16);
}
// pack two f32 -> two bf16 (round-half-up; cheap: 5 VALU per 2 values)
__device__ __forceinline__ unsigned pk2(float a, float b) {
    unsigned ua = __float_as_uint(a) + 0x8000u;
    unsigned ub = __float_as_uint(b) + 0x8000u;
    return (ua >> 16) | (ub & 0xFFFF0000u);
}

// 64x64 coalesced transpose tile: dst[(n0d+nn)*dstK + k0s+tx] = f2b(src[(k0s+tx)*srcStride + nc0+nn])
__device__ __forceinline__ void transpose_tile(
    const float* __restrict__ src, int srcStride, int nc0, int k0s,
    unsigned short* __restrict__ dst, int dstK, int n0d, int tid)
{
    __shared__ unsigned short T[64][66];   // stride 132B -> bank tx%32 on write, 2-way on read
    int tx = tid & 63, ty = tid >> 6;      // 4 rows per iteration
#pragma unroll
    for (int r = 0; r < 16; ++r) {
        int kk = ty + r * 4;
        T[tx][kk] = f2b(src[(size_t)(k0s + kk) * srcStride + nc0 + tx]);
    }
    __syncthreads();
#pragma unroll
    for (int r = 0; r < 16; ++r) {
        int nn = ty + r * 4;
        dst[(size_t)(n0d + nn) * dstK + k0s + tx] = T[nn][tx];
    }
}

// ------------------------------------------------ fused prep:
// blocks [0,128): LDS-tiled coalesced weight transposes
// blocks [128,384): h -> bf16 (coalesced, 8 elems/thread)
// blocks [384,640): edge bias + per-row edge lists
__global__ __launch_bounds__(256) void prep_all_kernel(
    const float* __restrict__ Wq, const float* __restrict__ Wk,
    const float* __restrict__ Wv, const float* __restrict__ Wo,
    const float* __restrict__ W1, const float* __restrict__ W2,
    const float* __restrict__ h, const float* __restrict__ ea,
    const float* __restrict__ We, const float* __restrict__ be,
    const int* __restrict__ ei,
    unsigned short* __restrict__ Wqkvt, unsigned short* __restrict__ Wot,
    unsigned short* __restrict__ W1t, unsigned short* __restrict__ W2t,
    unsigned short* __restrict__ hb,
    float* __restrict__ eb, int* __restrict__ cnt, int* __restrict__ lst)
{
    int b = blockIdx.x;
    if (b < 128) {
        const float* src; int srcStride, nc0, k0s, dstK, n0d;
        unsigned short* dst;
        if (b < 48) {                      // Wqkv: out 768x256
            int tn = b >> 2, tk = b & 3, n0 = tn * 64;
            src = (n0 < 256) ? Wq : (n0 < 512) ? Wk : Wv;
            srcStride = 256; nc0 = n0 & 255; k0s = tk * 64;
            dst = Wqkvt; dstK = 256; n0d = n0;
        } else if (b < 64) {               // Wo: out 256x256
            int t = b - 48, tn = t >> 2, tk = t & 3;
            src = Wo; srcStride = 256; nc0 = tn * 64; k0s = tk * 64;
            dst = Wot; dstK = 256; n0d = tn * 64;
        } else if (b < 96) {               // W1: out 512x256 (src 256x512)
            int t = b - 64, tn = t >> 2, tk = t & 3;
            src = W1; srcStride = 512; nc0 = tn * 64; k0s = tk * 64;
            dst = W1t; dstK = 256; n0d = tn * 64;
        } else {                           // W2: out 256x512 (src 512x256)
            int t = b - 96, tn = t >> 3, tk = t & 7;
            src = W2; srcStride = 256; nc0 = tn * 64; k0s = tk * 64;
            dst = W2t; dstK = 512; n0d = tn * 64;
        }
        transpose_tile(src, srcStride, nc0, k0s, dst, dstK, n0d, threadIdx.x);
    } else if (b < 384) {
        int j = ((b - 128) * 256 + threadIdx.x) * 8;     // 256 blocks cover 2048*256
        const float* hp = h + j;
        float4 f0 = *(const float4*)hp, f1 = *(const float4*)(hp + 4);
        uint4 pk = { pk2(f0.x, f0.y), pk2(f0.z, f0.w),
                     pk2(f1.x, f1.y), pk2(f1.z, f1.w) };
        *(uint4*)(hb + j) = pk;
    } else {
        int e = (b - 384) * 256 + threadIdx.x;
        float acc[NH];
#pragma unroll
        for (int hh = 0; hh < NH; ++hh) acc[hh] = be[hh];
#pragma unroll
        for (int f = 0; f < 7; ++f) {
            float x = ea[e * 7 + f];
#pragma unroll
            for (int hh = 0; hh < NH; ++hh) acc[hh] = fmaf(x, We[f * NH + hh], acc[hh]);
        }
#pragma unroll
        for (int hh = 0; hh < NH; ++hh)
            eb[e * NH + hh] = acc[hh] * 1.44269504088896f;   // pre-scale by log2(e)
        int s = ei[e];
        int p = atomicAdd(&cnt[s], 1);
        if (p < CAP) lst[s * CAP + p] = e;
    }
}

// per-row: dedup (winner = max edge id per dest) + bucket by m-tile (dest>>7)
__global__ __launch_bounds__(128) void rowprep_kernel(
    const int* __restrict__ ei, const int* __restrict__ cnt,
    const int* __restrict__ lst, int* __restrict__ sortedDest,
    int* __restrict__ sortedE, int* __restrict__ rowOff)
{
    __shared__ int ds[CAP], es[CAP];
    __shared__ int bc[16], off[17];
    int n = blockIdx.x, t = threadIdx.x;
    int c = cnt[n]; if (c > CAP) c = CAP;
    if (t < 16) bc[t] = 0;
    int e = -1, d = -1;
    if (t < c) { e = lst[n * CAP + t]; d = ei[NE + e]; }
    ds[t] = d; es[t] = e;
    __syncthreads();
    bool win = (t < c);
    if (win) {
        for (int j = 0; j < c; ++j)
            if (ds[j] == d && es[j] > e) { win = false; break; }
    }
    int bkt = (d >= 0) ? (d >> 7) : 0;
    int pos = -1;
    if (win) pos = atomicAdd(&bc[bkt], 1);
    __syncthreads();
    if (t == 0) {
        int s = 0;
        for (int i = 0; i < 16; ++i) { off[i] = s; s += bc[i]; }
        off[16] = s;
    }
    __syncthreads();
    if (win) {
        int p = off[bkt] + pos;
        sortedDest[n * CAP + p] = d;
        sortedE[n * CAP + p] = e;
    }
    if (t < 17) rowOff[n * 17 + t] = off[t];
}

// ---------------------------------------------------------------- MFMA GEMM
// C[M,N] = A[M,K] @ Bt[N,K]^T + bias. Tile MT(M) x 64(N), BK=128 chunks.
// EPI 2: QKV split epilogue. Q/K written HEAD-BLOCKED [NH][NN][32] (head is
// uniform per 16-col group; 16-lane 32B write segments unchanged). V transposed.
template <int EPI, int MT, int AF32>
__global__ __launch_bounds__(MT * 4) void gemm_bf16(
    const void* __restrict__ Av, const unsigned short* __restrict__ Bt,
    const float* __restrict__ bias0, const float* __restrict__ bias1,
    const float* __restrict__ bias2, const float* __restrict__ resid,
    void* __restrict__ out0, void* __restrict__ out1, void* __restrict__ out2,
    int M, int N, int K)
{
    __shared__ __align__(16) unsigned short As[MT][136];
    __shared__ __align__(16) unsigned short Bs[64][136];
    int tid = threadIdx.x;
    int wv = tid >> 6, l = tid & 63, l15 = l & 15, quad = l >> 4;
    int m0 = blockIdx.y * MT, n0 = blockIdx.x * 64;

    f32x4 acc[4];
#pragma unroll
    for (int i = 0; i < 4; ++i) acc[i] = (f32x4){0.f, 0.f, 0.f, 0.f};

    for (int k0 = 0; k0 < K; k0 += 128) {
        if (MT == 64) {
            int row = tid >> 2, cb = (tid & 3) * 32;
            if (AF32) {
                const float* ap = (const float*)Av + (size_t)(m0 + row) * K + k0 + cb;
#pragma unroll
                for (int i = 0; i < 4; ++i) {
                    float4 f0 = *(const float4*)(ap + i * 8);
                    float4 f1 = *(const float4*)(ap + i * 8 + 4);
                    uint4 pk = { pk2(f0.x, f0.y), pk2(f0.z, f0.w),
                                 pk2(f1.x, f1.y), pk2(f1.z, f1.w) };
                    *(uint4*)&As[row][cb + i * 8] = pk;
                }
            } else {
                const unsigned short* ap =
                    (const unsigned short*)Av + (size_t)(m0 + row) * K + k0 + cb;
#pragma unroll
                for (int i = 0; i < 4; ++i)
                    *(uint4*)&As[row][cb + i * 8] = *(const uint4*)(ap + i * 8);
            }
            const unsigned short* bp = Bt + (size_t)(n0 + row) * K + k0 + cb;
#pragma unroll
            for (int i = 0; i < 4; ++i)
                *(uint4*)&Bs[row][cb + i * 8] = *(const uint4*)(bp + i * 8);
        } else {
            int rowa = tid >> 2, cba = (tid & 3) * 32;       // 32 A rows
            const unsigned short* ap =
                (const unsigned short*)Av + (size_t)(m0 + rowa) * K + k0 + cba;
#pragma unroll
            for (int i = 0; i < 4; ++i)
                *(uint4*)&As[rowa][cba + i * 8] = *(const uint4*)(ap + i * 8);
            int rowb = tid >> 1, cbb = (tid & 1) * 64;       // 64 B rows
            const unsigned short* bp = Bt + (size_t)(n0 + rowb) * K + k0 + cbb;
#pragma unroll
            for (int i = 0; i < 8; ++i)
                *(uint4*)&Bs[rowb][cbb + i * 8] = *(const uint4*)(bp + i * 8);
        }
        __syncthreads();
#pragma unroll
        for (int ks = 0; ks < 4; ++ks) {
            bf16x8 a = *(const bf16x8*)&As[wv * 16 + l15][ks * 32 + quad * 8];
#pragma unroll
            for (int nt = 0; nt < 4; ++nt) {
                bf16x8 b = *(const bf16x8*)&Bs[nt * 16 + l15][ks * 32 + quad * 8];
                acc[nt] = __builtin_amdgcn_mfma_f32_16x16x32_bf16(a, b, acc[nt], 0, 0, 0);
            }
        }
        __syncthreads();
    }

#pragma unroll
    for (int nt = 0; nt < 4; ++nt) {
        int colb = n0 + nt * 16;                     // uniform per nt
        if (EPI == 2 && colb >= 512) {
            // V: write transposed into Vt[n][NN], rows quad*4..+3 packed
            int n = colb + l15 - 512;
            float bv = bias2[n];
            uint2 pk = { pk2(acc[nt][0] + bv, acc[nt][1] + bv),
                         pk2(acc[nt][2] + bv, acc[nt][3] + bv) };
            *(uint2*)((unsigned short*)out2 + (size_t)n * NN + m0 + wv * 16 + quad * 4) = pk;
            continue;
        }
#pragma unroll
        for (int r = 0; r < 4; ++r) {
            int row = m0 + wv * 16 + quad * 4 + r;
            int col = colb + l15;
            float v = acc[nt][r];
            if (EPI == 0) {
                v += bias0[col];
                if (resid) v += resid[(size_t)row * N + col];
                ((float*)out0)[(size_t)row * N + col] = v;
            } else if (EPI == 1) {
                v += bias0[col];
                v = 0.5f * v * (1.0f + erff(v * 0.70710678118654752f));
                ((unsigned short*)out0)[(size_t)row * N + col] = f2b(v);
            } else {
                if (col < 256) {
                    // fold 1/sqrt(32) * log2(e) into Q; head-blocked layout
                    v = (v + bias0[col]) * 0.2550348592f;
                    ((unsigned short*)out0)[(size_t)(col >> 5) * (NN * 32)
                        + (size_t)row * 32 + (col & 31)] = f2b(v);
                } else {
                    int kc = col - 256;
                    v += bias1[kc];
                    ((unsigned short*)out1)[(size_t)(kc >> 5) * (NN * 32)
                        + (size_t)row * 32 + (kc & 31)] = f2b(v);
                }
            }
        }
    }
}

// ---------------------------------------------------------------- attention
// Staged (round-2 structure: LDS K/V shared by 4 waves) + T14 async-STAGE
// prefetch: tile t+1's K/V global loads are ISSUED into registers right after
// the post-staging barrier, so their latency hides under tile t's
// QK^T + fixup + PV; the vmcnt wait lands at the next iteration's LDS write.
// Values bit-identical (staging order is value-irrelevant).
// grid (NN/64, NH, SPLIT), block 256 = 4 waves x 16 q-rows.
__global__ __launch_bounds__(256) void attn_mfma(
    const unsigned short* __restrict__ Qb, const unsigned short* __restrict__ Kb,
    const unsigned short* __restrict__ Vt, const float* __restrict__ eb,
    const int* __restrict__ sortedDest, const int* __restrict__ sortedE,
    const int* __restrict__ rowOff,
    float* __restrict__ accD, float* __restrict__ lD)
{
    __shared__ __align__(16) unsigned short Ks[TM2][40];          // K rows
    __shared__ __align__(16) unsigned short Vs[32][TM2 + 8];      // V^T rows
    __shared__ __align__(16) unsigned short Pn[4][16][TM2 + 16];  // per-wave P, [qrow][m]
    int h = blockIdx.y, tid = threadIdx.x;
    int wv = tid >> 6, l = tid & 63, l15 = l & 15, quad = l >> 4;
    int n0 = blockIdx.x * 64 + wv * 16;
    int mz = blockIdx.z;

    const unsigned short* Qh = Qb + (size_t)h * NN * 32;
    const unsigned short* Kh = Kb + (size_t)h * NN * 32;
    bf16x8 aq = *(const bf16x8*)(Qh + (size_t)(n0 + l15) * 32 + quad * 8);

    f32x4 oacc[2];
    oacc[0] = (f32x4){0.f, 0.f, 0.f, 0.f};
    oacc[1] = (f32x4){0.f, 0.f, 0.f, 0.f};
    float lacc = 0.f;                               // partial for q-row l15
    float dreg = 0.f;                               // fixup delta, row r16
    const unsigned short* Vth = Vt + (size_t)h * 32 * NN;

    int r16 = l >> 2, sub = l & 3;                  // fixup: 4 lanes per q-row
    int frow = n0 + r16;

    // staging coordinates (constant across tiles)
    int sr = tid >> 1, skc = (tid & 1) * 16;        // K: 2 threads/row, 32B each
    int sd = tid >> 3, smc = (tid & 7) * 16;        // V^T: 8 threads/row

    // prologue: load tile 0 into registers
    uint4 kA, kB, vA, vB;
    {
        int m0 = mz * (NN / SPLIT);
        const unsigned short* ks = Kh + (size_t)(m0 + sr) * 32 + skc;
        kA = *(const uint4*)ks; kB = *(const uint4*)(ks + 8);
        const unsigned short* vs = Vth + (size_t)sd * NN + m0 + smc;
        vA = *(const uint4*)vs; vB = *(const uint4*)(vs + 8);
    }

    for (int t = 0; t < NN / (TM2 * SPLIT); ++t) {
        int m0 = (mz * (NN / SPLIT)) + t * TM2;
        int ti = m0 >> 7;                           // global tile index 0..15
        // write prefetched registers to LDS (vmcnt wait lands here)
        *(uint4*)&Ks[sr][skc]     = kA;
        *(uint4*)&Ks[sr][skc + 8] = kB;
        *(uint4*)&Vs[sd][smc]     = vA;
        *(uint4*)&Vs[sd][smc + 8] = vB;
        __syncthreads();
        // issue tile t+1 loads now; they complete under this tile's compute
        if (t + 1 < NN / (TM2 * SPLIT)) {
            int m1 = m0 + TM2;
            const unsigned short* ks = Kh + (size_t)(m1 + sr) * 32 + skc;
            kA = *(const uint4*)ks; kB = *(const uint4*)(ks + 8);
            const unsigned short* vs = Vth + (size_t)sd * NN + m1 + smc;
            vA = *(const uint4*)vs; vB = *(const uint4*)(vs + 8);
        }
        // S^T = K Q^T, p = 2^s, packed b64 stores into A-operand layout
#pragma unroll
        for (int mt = 0; mt < TM2 / 16; ++mt) {
            bf16x8 ak = *(const bf16x8*)&Ks[mt * 16 + l15][quad * 8];
            f32x4 s = __builtin_amdgcn_mfma_f32_16x16x32_bf16(
                ak, aq, (f32x4){0.f, 0.f, 0.f, 0.f}, 0, 0, 0);
            float p0 = __builtin_amdgcn_exp2f(s[0]);
            float p1 = __builtin_amdgcn_exp2f(s[1]);
            float p2 = __builtin_amdgcn_exp2f(s[2]);
            float p3 = __builtin_amdgcn_exp2f(s[3]);
            lacc += (p0 + p1) + (p2 + p3);
            *(uint2*)&Pn[wv][l15][mt * 16 + quad * 4] =
                (uint2){pk2(p0, p1), pk2(p2, p3)};
        }
        WAVE_LDS_SYNC();   // Pn is wave-private: wave-local visibility suffices
        // sparse bias fixup: P[row][d] *= 2^b; dreg += p_old*(2^b - 1)
        {
            int o0 = rowOff[frow * 17 + ti];
            int o1 = rowOff[frow * 17 + ti + 1];
            for (int idx = o0 + sub; idx < o1; idx += 4) {
                int d = sortedDest[frow * CAP + idx] - m0;   // 0..127
                int e = sortedE[frow * CAP + idx];
                float expb = __builtin_amdgcn_exp2f(eb[e * NH + h]);
                float pold = b2f(Pn[wv][r16][d]);
                Pn[wv][r16][d] = f2b(pold * expb);
                dreg += pold * (expb - 1.0f);
            }
        }
        WAVE_LDS_SYNC();
        // O += P @ V  (A-frags from Pn, B-frags from Vs)
#pragma unroll
        for (int kc = 0; kc < TM2 / 32; ++kc) {
            bf16x8 ap = *(const bf16x8*)&Pn[wv][l15][kc * 32 + quad * 8];
#pragma unroll
            for (int nt = 0; nt < 2; ++nt) {
                bf16x8 bv = *(const bf16x8*)&Vs[nt * 16 + l15][kc * 32 + quad * 8];
                oacc[nt] = __builtin_amdgcn_mfma_f32_16x16x32_bf16(ap, bv, oacc[nt], 0, 0, 0);
            }
        }
        __syncthreads();   // all waves done with Ks/Vs before restage
    }

    // reduce: lacc over quads; dreg over the 4 sub-lanes of each row
    lacc += __shfl_xor(lacc, 16);
    lacc += __shfl_xor(lacc, 32);
    dreg += __shfl_xor(dreg, 1);
    dreg += __shfl_xor(dreg, 2);
    float dtot = __shfl(dreg, l15 * 4);             // row l15's total delta
    float* lDp = lD + (size_t)mz * NN * NH;
    if (l < 16)
        lDp[(size_t)(n0 + l) * NH + h] = lacc + dtot;
    float* aDp = accD + (size_t)mz * NN * DM;
#pragma unroll
    for (int nt = 0; nt < 2; ++nt)
#pragma unroll
        for (int r = 0; r < 4; ++r)
            aDp[(size_t)(n0 + quad * 4 + r) * DM + h * 32 + nt * 16 + l15] = oacc[nt][r];
}

// ------------------------------------------- fused tail (barrier-free GEMMs):
// T = h + (sum accD / sum lD) @ Wo + bo ; H1 = LN(T) ; X2 = bf16(LN(H1))
// F1 = gelu(X2 @ W1 + b1) ; out = H1 + F1 @ W2 + b2
// Weights L2-resident: B-fragments loaded directly from global into MFMA
// operands; no barriers inside the K-loops. 512 threads = 8 waves.
__global__ __launch_bounds__(512) void tail_fused_kernel(
    const float* __restrict__ accD, const float* __restrict__ lD,
    const unsigned short* __restrict__ Wot, const float* __restrict__ bo,
    const float* __restrict__ h, const float* __restrict__ ln1g,
    const float* __restrict__ ln1b, const float* __restrict__ flng,
    const float* __restrict__ flnb,
    const unsigned short* __restrict__ W1t, const float* __restrict__ fb1,
    const unsigned short* __restrict__ W2t, const float* __restrict__ fb2,
    float* __restrict__ out)
{
    __shared__ float linv[16][8];
    __shared__ __align__(16) unsigned short As[16][264];    // attn-out bf16
    __shared__ float Tt[16][264];                            // T, then H1 (f32)
    __shared__ __align__(16) unsigned short X2s[16][264];   // LN2 output bf16
    __shared__ __align__(16) unsigned short F1s[16][520];   // gelu output bf16
    int tid = threadIdx.x, m0 = blockIdx.x * 16;
    int wv = tid >> 6, l = tid & 63, l15 = l & 15, quad = l >> 4;

    if (tid < 128) {
        int r = tid >> 3, hh = tid & 7;
        float ls = 0.f;
#pragma unroll
        for (int s = 0; s < SPLIT; ++s)
            ls += lD[(size_t)s * NN * NH + (size_t)(m0 + r) * NH + hh];
        linv[r][hh] = 1.0f / ls;
    }
    __syncthreads();
    {   // As fill: 512 threads cover 2 rows x 256 cols per iteration
        int col = tid & 255, rh = tid >> 8;
#pragma unroll
        for (int ch = 0; ch < 8; ++ch) {
            int row = ch * 2 + rh;
            float o = 0.f;
#pragma unroll
            for (int s = 0; s < SPLIT; ++s)
                o += accD[(size_t)s * NN * DM + (size_t)(m0 + row) * DM + col];
            As[row][col] = f2b(o * linv[row][col >> 5]);
        }
    }
    __syncthreads();

    // ---- GEMM 1: AO @ Wo  (16x256, K=256) — B direct from global, no barriers
    f32x4 acc[2];
    acc[0] = (f32x4){0.f, 0.f, 0.f, 0.f};
    acc[1] = (f32x4){0.f, 0.f, 0.f, 0.f};
#pragma unroll
    for (int k0 = 0; k0 < 256; k0 += 32) {
        bf16x8 a = *(const bf16x8*)&As[l15][k0 + quad * 8];
#pragma unroll
        for (int nt = 0; nt < 2; ++nt) {
            int row = wv * 32 + nt * 16 + l15;
            bf16x8 b = *(const bf16x8*)(Wot + (size_t)row * 256 + k0 + quad * 8);
            acc[nt] = __builtin_amdgcn_mfma_f32_16x16x32_bf16(a, b, acc[nt], 0, 0, 0);
        }
    }
#pragma unroll
    for (int nt = 0; nt < 2; ++nt)
#pragma unroll
        for (int r = 0; r < 4; ++r) {
            int row = quad * 4 + r, col = wv * 32 + nt * 16 + l15;
            Tt[row][col] = acc[nt][r] + bo[col] + h[(size_t)(m0 + row) * DM + col];
        }
    __syncthreads();

    // ---- double LN: 16 lanes per row (waves 0..3, identical to before)
    if (tid < 256) {
        int rr = tid >> 4, l16 = tid & 15;
        float x[16];
#pragma unroll
        for (int j = 0; j < 16; ++j) x[j] = Tt[rr][l16 + 16 * j];
        float mu = 0.f;
#pragma unroll
        for (int j = 0; j < 16; ++j) mu += x[j];
#pragma unroll
        for (int off = 1; off < 16; off <<= 1) mu += __shfl_xor(mu, off);
        mu *= (1.0f / 256.0f);
        float var = 0.f;
#pragma unroll
        for (int j = 0; j < 16; ++j) { float d = x[j] - mu; var += d * d; }
#pragma unroll
        for (int off = 1; off < 16; off <<= 1) var += __shfl_xor(var, off);
        float rs = rsqrtf(var * (1.0f / 256.0f) + 1e-5f);
        float y[16]; float mu2 = 0.f;
#pragma unroll
        for (int j = 0; j < 16; ++j) {
            int c = l16 + 16 * j;
            y[j] = (x[j] - mu) * rs * ln1g[c] + ln1b[c];
            mu2 += y[j];
        }
#pragma unroll
        for (int off = 1; off < 16; off <<= 1) mu2 += __shfl_xor(mu2, off);
        mu2 *= (1.0f / 256.0f);
        float var2 = 0.f;
#pragma unroll
        for (int j = 0; j < 16; ++j) { float d = y[j] - mu2; var2 += d * d; }
#pragma unroll
        for (int off = 1; off < 16; off <<= 1) var2 += __shfl_xor(var2, off);
        float rs2 = rsqrtf(var2 * (1.0f / 256.0f) + 1e-5f);
#pragma unroll
        for (int j = 0; j < 16; ++j) {
            int c = l16 + 16 * j;
            Tt[rr][c] = y[j];                               // H1 (kept for residual)
            X2s[rr][c] = f2b((y[j] - mu2) * rs2 * flng[c] + flnb[c]);
        }
    }
    __syncthreads();

    // ---- GEMM 2: X2 @ W1 -> gelu -> F1s  (16x512, K=256)
    f32x4 acc1[4];
#pragma unroll
    for (int i = 0; i < 4; ++i) acc1[i] = (f32x4){0.f, 0.f, 0.f, 0.f};
#pragma unroll
    for (int k0 = 0; k0 < 256; k0 += 32) {
        bf16x8 a = *(const bf16x8*)&X2s[l15][k0 + quad * 8];
#pragma unroll
        for (int nt = 0; nt < 4; ++nt) {
            int row = wv * 64 + nt * 16 + l15;
            bf16x8 b = *(const bf16x8*)(W1t + (size_t)row * 256 + k0 + quad * 8);
            acc1[nt] = __builtin_amdgcn_mfma_f32_16x16x32_bf16(a, b, acc1[nt], 0, 0, 0);
        }
    }
#pragma unroll
    for (int nt = 0; nt < 4; ++nt)
#pragma unroll
        for (int r = 0; r < 4; ++r) {
            int row = quad * 4 + r, col = wv * 64 + nt * 16 + l15;
            float v = acc1[nt][r] + fb1[col];
            v = 0.5f * v * (1.0f + erff(v * 0.70710678118654752f));
            F1s[row][col] = f2b(v);
        }
    __syncthreads();

    // ---- GEMM 3: F1 @ W2 + b2 + H1 -> out  (16x256, K=512)
    f32x4 acc2[2];
    acc2[0] = (f32x4){0.f, 0.f, 0.f, 0.f};
    acc2[1] = (f32x4){0.f, 0.f, 0.f, 0.f};
#pragma unroll
    for (int k0 = 0; k0 < 512; k0 += 32) {
        bf16x8 a = *(const bf16x8*)&F1s[l15][k0 + quad * 8];
#pragma unroll
        for (int nt = 0; nt < 2; ++nt) {
            int row = wv * 32 + nt * 16 + l15;
            bf16x8 b = *(const bf16x8*)(W2t + (size_t)row * 512 + k0 + quad * 8);
            acc2[nt] = __builtin_amdgcn_mfma_f32_16x16x32_bf16(a, b, acc2[nt], 0, 0, 0);
        }
    }
#pragma unroll
    for (int nt = 0; nt < 2; ++nt)
#pragma unroll
        for (int r = 0; r < 4; ++r) {
            int row = quad * 4 + r, col = wv * 32 + nt * 16 + l15;
            out[(size_t)(m0 + row) * DM + col] = acc2[nt][r] + fb2[col] + Tt[row][col];
        }
}

// ---------------------------------------------------------------- launch
extern "C" void kernel_launch(void* const* d_in, const int* in_sizes, int n_in,
                              void* d_out, int out_size, void* d_ws, size_t ws_size,
                              hipStream_t stream)
{
    const float* h    = (const float*)d_in[0];
    const float* ea   = (const float*)d_in[1];
    const float* Wq   = (const float*)d_in[2];
    const float* bq   = (const float*)d_in[3];
    const float* Wk   = (const float*)d_in[4];
    const float* bk   = (const float*)d_in[5];
    const float* Wv   = (const float*)d_in[6];
    const float* bv   = (const float*)d_in[7];
    const float* Wo   = (const float*)d_in[8];
    const float* bo   = (const float*)d_in[9];
    const float* We   = (const float*)d_in[10];
    const float* be   = (const float*)d_in[11];
    const float* ln1g = (const float*)d_in[12];
    const float* ln1b = (const float*)d_in[13];
    const float* flng = (const float*)d_in[14];
    const float* flnb = (const float*)d_in[15];
    const float* W1   = (const float*)d_in[16];
    const float* b1   = (const float*)d_in[17];
    const float* W2   = (const float*)d_in[18];
    const float* b2   = (const float*)d_in[19];
    const int*   ei   = (const int*)d_in[20];
    float* out = (float*)d_out;

    char* p = (char*)d_ws;
    float* eb   = (float*)p;           p += (size_t)NE * NH * 4;        // 2 MB
    int*   cnt  = (int*)p;             p += (size_t)NN * 4;
    int*   lst  = (int*)p;             p += (size_t)NN * CAP * 4;       // 1 MB
    int*   sD   = (int*)p;             p += (size_t)NN * CAP * 4;       // 1 MB
    int*   sE   = (int*)p;             p += (size_t)NN * CAP * 4;       // 1 MB
    int*   rOff = (int*)p;             p += (size_t)NN * 17 * 4;
    unsigned short* Wqkvt = (unsigned short*)p; p += (size_t)768 * 256 * 2;
    unsigned short* Wot   = (unsigned short*)p; p += (size_t)256 * 256 * 2;
    unsigned short* W1t   = (unsigned short*)p; p += (size_t)512 * 256 * 2;
    unsigned short* W2t   = (unsigned short*)p; p += (size_t)256 * 512 * 2;
    unsigned short* hb    = (unsigned short*)p; p += (size_t)NN * DM * 2;
    unsigned short* Qb    = (unsigned short*)p; p += (size_t)NN * DM * 2;
    unsigned short* Kb    = (unsigned short*)p; p += (size_t)NN * DM * 2;
    unsigned short* Vt    = (unsigned short*)p; p += (size_t)NN * DM * 2;
    float* accD = (float*)p;           p += (size_t)SPLIT * NN * DM * 4; // 8 MB
    float* lD   = (float*)p;           p += (size_t)SPLIT * NN * NH * 4;

    hipMemsetAsync(cnt, 0, (size_t)NN * 4, stream);
    prep_all_kernel<<<384 + NE / 256, 256, 0, stream>>>(
        Wq, Wk, Wv, Wo, W1, W2, h, ea, We, be, ei,
        Wqkvt, Wot, W1t, W2t, hb, eb, cnt, lst);
    rowprep_kernel<<<NN, 128, 0, stream>>>(ei, cnt, lst, sD, sE, rOff);

    // fused QKV: [2048 x 768] = hb(bf16) @ [Wq|Wk|Wv]; Q/K head-blocked out
    gemm_bf16<2, 64, 0><<<dim3(768 / 64, NN / 64), 256, 0, stream>>>(
        hb, Wqkvt, bq, bk, bv, nullptr, Qb, Kb, Vt, NN, 768, 256);

    attn_mfma<<<dim3(NN / 64, NH, SPLIT), 256, 0, stream>>>(
        Qb, Kb, Vt, eb, sD, sE, rOff, accD, lD);

    // fused tail: Wo GEMM + LN1 + LN2 + FFN1 + gelu + FFN2 + residual
    tail_fused_kernel<<<NN / 16, 512, 0, stream>>>(
        accD, lD, Wot, bo, h, ln1g, ln1b, flng, flnb,
        W1t, b1, W2t, b2, out);
}